// Round 3
// baseline (17811.807 us; speedup 1.0000x reference)
//
#include <hip/hip_runtime.h>
#include <math.h>

// ---------------- problem constants ----------------
#define NBLK 256
#define NTHR 256
#define NL0B 128      // blocks 0..127 -> layer0 (8 h-cols each), 128..255 -> layer1
#define BATCH 64
#define TT 512
#define INF 256
#define OUTF 256

typedef _Float16 f16;
typedef __attribute__((ext_vector_type(4))) _Float16 f16x4;
typedef __attribute__((ext_vector_type(8))) _Float16 f16x8;
typedef __attribute__((ext_vector_type(4))) float f32x4;

// Activation buffers in d_ws (fp16, hi/lo split along K):
// A0[p]: [64][2560] = [x_hi(0..255) | s0_hi(256..1279) | x_lo(1280..1535) | s0_lo(1536..2559)]
// A1[p]: [64][4096] = [s0_hi(0..1023) | s1_hi(1024..2047) | s0_lo(2048..3071) | s1_lo(3072..4095)]
#define AW0 2560
#define AW1 4096
#define KP0 1280
#define KP1 2048
#define A0_ELEMS (BATCH*AW0)
#define A1_ELEMS (BATCH*AW1)
#define A1_OFF (2*A0_ELEMS)
#define FLAGS_OFF_BYTES ((size_t)(A1_OFF + 2*A1_ELEMS)*2)
#define WS_BYTES (FLAGS_OFF_BYTES + NBLK*4)

// LDS: fp16 weight slice only, k-chunked [KPHYS/8][32 cols][8] = 128 KiB max (L1 layer)
#define LDS_BYTES 131072

// 40 ms at the 100 MHz s_memrealtime clock: ~1000x normal barrier wait.
#define BARRIER_DEADLINE_TICKS 4000000ull

__device__ __forceinline__ float sig_(float v) { return 1.0f / (1.0f + __expf(-v)); }

// Flag-per-block barrier, deadline-bounded. Block b publishes flags[b]=tgt
// (release/agent -> cross-XCD visibility); wave 0 polls all 256 flags
// (4 per lane). On deadline, sets sticky `bail` -> no further spinning ever
// (bounded kernel runtime even if co-residency failed).
__device__ __forceinline__ void grid_barrier(int* flags, int tgt, bool& bail) {
  __syncthreads();
  if (threadIdx.x == 0)
    __hip_atomic_store(&flags[blockIdx.x], tgt, __ATOMIC_RELEASE, __HIP_MEMORY_SCOPE_AGENT);
  if (threadIdx.x < 64 && !bail) {
    const unsigned long long t0 = __builtin_amdgcn_s_memrealtime();
    for (;;) {
      int ok = 1;
#pragma unroll
      for (int q = 0; q < 4; ++q)
        ok &= (__hip_atomic_load(&flags[threadIdx.x + q * 64],
                                 __ATOMIC_RELAXED, __HIP_MEMORY_SCOPE_AGENT) >= tgt);
      if (__all(ok)) break;
      if (__builtin_amdgcn_s_memrealtime() - t0 > BARRIER_DEADLINE_TICKS) { bail = true; break; }
      __builtin_amdgcn_s_sleep(2);
    }
    (void)__hip_atomic_load(&flags[threadIdx.x], __ATOMIC_ACQUIRE, __HIP_MEMORY_SCOPE_AGENT);
  }
  __syncthreads();
}

// One LSTM step. Each wave: one batch-quadrant (16 rows) x 32 gate cols x full K.
// n-tile0 cols = [i(0-7)|f(8-15)], n-tile1 = [g|o]. No cross-wave reduction.
template<int AW, int KPHYS, bool IS_L1>
__device__ __forceinline__ void round_body(
    const f16* __restrict__ A, f16* __restrict__ a0n, f16* __restrict__ a1n,
    const f16* __restrict__ wl, float* creg,
    float bi, float bf_, float bg, float bo, int hc0, int wave, int lane)
{
  const int col = lane & 15, krow = lane >> 4;
  f32x4 aHi0 = (f32x4){0.f,0.f,0.f,0.f}, aHi1 = (f32x4){0.f,0.f,0.f,0.f};
  f32x4 aLo0 = (f32x4){0.f,0.f,0.f,0.f}, aLo1 = (f32x4){0.f,0.f,0.f,0.f};
  const f16* Ab = A + (size_t)(16 * wave + col) * AW + krow * 8;
  const f16* Wb = wl + krow * 256 + col * 8;
#pragma unroll 4
  for (int it = 0; it < (KPHYS >> 5); ++it) {
    f16x8 ah = *(const f16x8*)(Ab + it * 32);
    f16x8 al = *(const f16x8*)(Ab + KPHYS + it * 32);
    f16x8 w0 = *(const f16x8*)(Wb + it * 1024);
    f16x8 w1 = *(const f16x8*)(Wb + it * 1024 + 128);
    aHi0 = __builtin_amdgcn_mfma_f32_16x16x32_f16(ah, w0, aHi0, 0, 0, 0);
    aHi1 = __builtin_amdgcn_mfma_f32_16x16x32_f16(ah, w1, aHi1, 0, 0, 0);
    aLo0 = __builtin_amdgcn_mfma_f32_16x16x32_f16(al, w0, aLo0, 0, 0, 0);
    aLo1 = __builtin_amdgcn_mfma_f32_16x16x32_f16(al, w1, aLo1, 0, 0, 0);
  }
  f32x4 accA = aHi0 + aLo0;   // [i|f]
  f32x4 accB = aHi1 + aLo1;   // [g|o]
#pragma unroll
  for (int j = 0; j < 4; ++j) {
    float iv = accA[j], gv = accB[j];
    float fv = __shfl_xor(iv, 8, 64);   // partner lane col^8: f at same row
    float ov = __shfl_xor(gv, 8, 64);   // and o
    if (col < 8) {
      const int row = 16 * wave + krow * 4 + j;   // batch row (C/D: row=krow*4+reg)
      const int hc = hc0 + col;
      iv += bi; fv += bf_; gv += bg; ov += bo;
      float cn = sig_(fv) * creg[j] + sig_(iv) * tanhf(gv);
      float hn = sig_(ov) * tanhf(cn);
      creg[j] = cn;
      f16 hh = (f16)hn;
      f16 hl = (f16)(hn - (float)hh);
      if (!IS_L1) {
        a0n[(size_t)row * AW0 + 256 + hc]  = hh;
        a0n[(size_t)row * AW0 + 1536 + hc] = hl;
        a1n[(size_t)row * AW1 + hc]        = hh;
        a1n[(size_t)row * AW1 + 2048 + hc] = hl;
      } else {
        a1n[(size_t)row * AW1 + 1024 + hc] = hh;
        a1n[(size_t)row * AW1 + 3072 + hc] = hl;
      }
    }
  }
}

__global__ __launch_bounds__(NTHR, 1) void lstm_fused(
    const float* __restrict__ x,
    const float* __restrict__ w_ih_0, const float* __restrict__ w_hh_0,
    const float* __restrict__ b_ih_0, const float* __restrict__ b_hh_0,
    const float* __restrict__ w_ih_1, const float* __restrict__ w_hh_1,
    const float* __restrict__ b_ih_1, const float* __restrict__ b_hh_1,
    const float* __restrict__ w_fc, const float* __restrict__ b_fc,
    float* __restrict__ out, void* __restrict__ ws)
{
  extern __shared__ char smem[];
  f16* wl = (f16*)smem;
  f16* ws16 = (f16*)ws;
  int* flags = (int*)((char*)ws + FLAGS_OFF_BYTES);

  const int b = blockIdx.x;
  const int tid = threadIdx.x;
  const int wave = tid >> 6, lane = tid & 63;
  const int col = lane & 15;
  const bool isL1 = (b >= NL0B);
  const int bb = isL1 ? b - NL0B : b;
  const int hc0 = bb * 8;
  const int KPHYS = isL1 ? KP1 : KP0;
  bool bail = false;

  // ---- stage fp16 weight slice into LDS, k-chunked [K/8][32][8] ----
  {
    const int c = tid >> 3, kpart = tid & 7;
    const int grp = c >> 3, sub = c & 7;           // gate group i/f/g/o
    const int grow = grp * 1024 + hc0 + sub;       // global gate row
    const int kbound = isL1 ? 1024 : 256;
    const float* srcA = isL1 ? (w_ih_1 + (size_t)grow * 1024) : (w_ih_0 + (size_t)grow * 256);
    const float* srcB = isL1 ? (w_hh_1 + (size_t)grow * 1024) : (w_hh_0 + (size_t)grow * 1024);
    const int kper = KPHYS >> 3;
    for (int k = kpart * kper; k < kpart * kper + kper; k += 4) {
      const float* s = (k < kbound) ? (srcA + k) : (srcB + (k - kbound));
      float4 v = *(const float4*)s;
      f16x4 hv;
      hv[0] = (f16)v.x; hv[1] = (f16)v.y; hv[2] = (f16)v.z; hv[3] = (f16)v.w;
      *(f16x4*)&wl[((size_t)(k >> 3) * 32 + c) * 8 + (k & 7)] = hv;
    }
  }

  // ---- per-lane bias registers (only cols 0-7 of each n-tile use them) ----
  float bi, bf_, bg, bo;
  {
    const float* bI = isL1 ? b_ih_1 : b_ih_0;
    const float* bH = isL1 ? b_hh_1 : b_hh_0;
    const int gi = hc0 + (col & 7);
    bi  = bI[gi]        + bH[gi];
    bf_ = bI[1024 + gi] + bH[1024 + gi];
    bg  = bI[2048 + gi] + bH[2048 + gi];
    bo  = bI[3072 + gi] + bH[3072 + gi];
  }
  float creg[4] = {0.f, 0.f, 0.f, 0.f};   // c-state in registers

  // ---- x[t=0] hi/lo into parity-0 A0 (each block stages one input column) ----
  if (tid < BATCH) {
    float v = x[((size_t)tid * TT + 0) * INF + b];
    f16 hi = (f16)v, lo = (f16)(v - (float)hi);
    ws16[(size_t)tid * AW0 + b] = hi;
    ws16[(size_t)tid * AW0 + 1280 + b] = lo;
  }
  grid_barrier(flags, 1, bail);

  // ---- 513 pipelined rounds: L0 does step r, L1 does step r-1 ----
  for (int r = 0; r <= TT; ++r) {
    f16* a0c = ws16 + (size_t)(r & 1) * A0_ELEMS;
    f16* a0n = ws16 + (size_t)((r + 1) & 1) * A0_ELEMS;
    f16* a1c = ws16 + A1_OFF + (size_t)(r & 1) * A1_ELEMS;
    f16* a1n = ws16 + A1_OFF + (size_t)((r + 1) & 1) * A1_ELEMS;

    if (!isL1) {
      if (r < TT)
        round_body<AW0, KP0, false>(a0c, a0n, a1n, wl, creg, bi, bf_, bg, bo, hc0, wave, lane);
      if ((r + 1) < TT && tid < 128) {   // stage x[t=r+1]
        const int row = tid >> 1, xc = 2 * b + (tid & 1);
        float v = x[((size_t)row * TT + (r + 1)) * INF + xc];
        f16 hi = (f16)v, lo = (f16)(v - (float)hi);
        a0n[(size_t)row * AW0 + xc] = hi;
        a0n[(size_t)row * AW0 + 1280 + xc] = lo;
      }
    } else {
      if (r >= 1)
        round_body<AW1, KP1, true>(a1c, nullptr, a1n, wl, creg, bi, bf_, bg, bo, hc0, wave, lane);
    }
    grid_barrier(flags, r + 2, bail);
  }

  // ---- FC on last timestep: out[:, b] = s1[511] . w_fc[b,:] + b_fc[b] ----
  {
    float* red = (float*)smem;   // weights no longer needed
    const f16* A = ws16 + A1_OFF + (size_t)1 * A1_ELEMS;  // parity (TT+1)&1 == 1
    const int row = tid & 63, kq = tid >> 6;
    const f16* ph = A + (size_t)row * AW1 + 1024 + kq * 256;
    const f16* pl = A + (size_t)row * AW1 + 3072 + kq * 256;
    const float* pw = w_fc + (size_t)b * 1024 + kq * 256;
    float acc = 0.f;
    for (int k = 0; k < 256; ++k)
      acc = fmaf((float)ph[k] + (float)pl[k], pw[k], acc);
    red[tid] = acc;
    __syncthreads();
    if (tid < 64) {
      float s = red[tid] + red[64 + tid] + red[128 + tid] + red[192 + tid] + b_fc[b];
      out[(size_t)tid * OUTF + b] = s;
    }
  }
}

extern "C" void kernel_launch(void* const* d_in, const int* in_sizes, int n_in,
                              void* d_out, int out_size, void* d_ws, size_t ws_size,
                              hipStream_t stream) {
  const float* x      = (const float*)d_in[0];
  const float* w_ih_0 = (const float*)d_in[1];
  const float* w_hh_0 = (const float*)d_in[2];
  const float* b_ih_0 = (const float*)d_in[3];
  const float* b_hh_0 = (const float*)d_in[4];
  const float* w_ih_1 = (const float*)d_in[5];
  const float* w_hh_1 = (const float*)d_in[6];
  const float* b_ih_1 = (const float*)d_in[7];
  const float* b_hh_1 = (const float*)d_in[8];
  const float* w_fc   = (const float*)d_in[9];
  const float* b_fc   = (const float*)d_in[10];
  float* out = (float*)d_out;
  void* ws = d_ws;

  // Workspace guard: never write past d_ws (an async VM fault kills the
  // container with no diagnostics). If too small, launch nothing -> clean
  // absmax-failure signature instead.
  if (ws_size < WS_BYTES) return;

  hipMemsetAsync(d_ws, 0, WS_BYTES, stream);
  hipFuncSetAttribute((const void*)lstm_fused,
                      hipFuncAttributeMaxDynamicSharedMemorySize, LDS_BYTES);

  void* args[] = {
    (void*)&x, (void*)&w_ih_0, (void*)&w_hh_0, (void*)&b_ih_0, (void*)&b_hh_0,
    (void*)&w_ih_1, (void*)&w_hh_1, (void*)&b_ih_1, (void*)&b_hh_1,
    (void*)&w_fc, (void*)&b_fc, (void*)&out, (void*)&ws
  };
  hipError_t err = hipLaunchCooperativeKernel((void*)lstm_fused, dim3(NBLK), dim3(NTHR),
                                              args, LDS_BYTES, stream);
  if (err != hipSuccess) {
    (void)hipGetLastError();   // clear sticky error, fall back to plain launch:
    // grid=256=#CUs, 128 KiB LDS -> 1 block/CU -> all blocks co-resident.
    lstm_fused<<<dim3(NBLK), dim3(NTHR), LDS_BYTES, stream>>>(
        x, w_ih_0, w_hh_0, b_ih_0, b_hh_0, w_ih_1, w_hh_1, b_ih_1, b_hh_1,
        w_fc, b_fc, out, ws);
  }
}

// Round 4
// 6826.048 us; speedup vs baseline: 2.6094x; 2.6094x over previous
//
#include <hip/hip_runtime.h>
#include <math.h>

// ---------------- problem constants ----------------
#define NBLK 256
#define NTHR 256
#define NL0B 128      // blocks 0..127 -> layer0 (8 h-cols each), 128..255 -> layer1
#define BATCH 64
#define TT 512
#define INF 256
#define OUTF 256

typedef _Float16 f16;
typedef __attribute__((ext_vector_type(4))) _Float16 f16x4;
typedef __attribute__((ext_vector_type(8))) _Float16 f16x8;
typedef __attribute__((ext_vector_type(4))) float f32x4;
typedef __attribute__((ext_vector_type(4))) int i32x4;

// Workspace: S0[2] rings then S1[2] rings ([64][1024] f16 = 128 KiB each), flags.
// ALL S accesses are sc0+sc1 (L1/L2-bypass, L3-coherent) -> no fences needed.
#define SBUF_ELEMS 65536
#define S1_BASE (2 * SBUF_ELEMS)
#define FLAGS_OFF_BYTES ((size_t)4 * SBUF_ELEMS * 2)   // 512 KiB
#define WS_BYTES (FLAGS_OFF_BYTES + NBLK * 4)

// LDS: fp16 weight slice, k-chunked [KPHYS/8][32 cols][8]; L1 layer = 128 KiB.
#define LDS_BYTES 131072

// 40 ms at the 100 MHz s_memrealtime clock (sticky bail -> bounded runtime).
#define BARRIER_DEADLINE_TICKS 4000000ull

__device__ __forceinline__ float sig_(float v) { return 1.0f / (1.0f + __expf(-v)); }

// ---- asm helpers: explicit sc0 sc1 (coherent at L3 across XCDs) ----
#define GLOAD16(dst, p) \
  asm volatile("global_load_dwordx4 %0, %1, off sc0 sc1" : "=v"(dst) : "v"(p))

#define VWAIT(N) do { \
  asm volatile("s_waitcnt vmcnt(" #N ")" ::: "memory"); \
  __builtin_amdgcn_sched_barrier(0); } while (0)

#define ISSUE32(BASEPTR, O0) do { \
  _Pragma("unroll") \
  for (int it_ = 0; it_ < 32; ++it_) { \
    const f16* p_ = (BASEPTR) + it_ * 32; \
    GLOAD16(av[(O0) + it_], p_); \
  } } while (0)

// consume 8 k-iterations (k-chunk of 32 each) starting at av[I0], weight 1024-chunk KOFF
#define CONS8(I0, KOFF) do { \
  _Pragma("unroll") \
  for (int q_ = 0; q_ < 8; ++q_) { \
    f16x8 a_ = __builtin_bit_cast(f16x8, av[(I0) + q_]); \
    const f16* wp_ = Wb + ((KOFF) + q_) * 1024; \
    f16x8 w0_ = *(const f16x8*)(wp_); \
    f16x8 w1_ = *(const f16x8*)(wp_ + 128); \
    acc0 = __builtin_amdgcn_mfma_f32_16x16x32_f16(a_, w0_, acc0, 0, 0, 0); \
    acc1 = __builtin_amdgcn_mfma_f32_16x16x32_f16(a_, w1_, acc1, 0, 0, 0); \
  } } while (0)

// Grid barrier: per-wave store-drain -> flag store (sc1) -> poll 256 flags with
// one dwordx4 per lane. No cache maintenance anywhere. Deadline-bail sticky.
__device__ __forceinline__ void grid_barrier(int* flags, int tgt, bool& bail) {
  asm volatile("s_waitcnt vmcnt(0)" ::: "memory");   // each wave drains its sc1 stores
  __syncthreads();
  if (threadIdx.x == 0) {
    int* fp = flags + blockIdx.x;
    asm volatile("global_store_dword %0, %1, off sc0 sc1" :: "v"(fp), "v"(tgt) : "memory");
  }
  if (threadIdx.x < 64 && !bail) {
    const int* pp = flags + (threadIdx.x << 2);
    const unsigned long long t0 = __builtin_amdgcn_s_memrealtime();
    for (;;) {
      i32x4 f4;
      asm volatile("global_load_dwordx4 %0, %1, off sc0 sc1\n\ts_waitcnt vmcnt(0)"
                   : "=v"(f4) : "v"(pp) : "memory");
      int ok = (f4[0] >= tgt) & (f4[1] >= tgt) & (f4[2] >= tgt) & (f4[3] >= tgt);
      if (__all(ok)) break;
      if (__builtin_amdgcn_s_memrealtime() - t0 > BARRIER_DEADLINE_TICKS) { bail = true; break; }
      __builtin_amdgcn_s_sleep(2);
    }
  }
  __syncthreads();
}

// LSTM nonlinearity + h store (4 rows/lane, cols<8 of each 16-wide n-tile).
__device__ __forceinline__ void epilogue_store(
    f32x4 acc0, f32x4 acc1, float* creg,
    float bi, float bf_, float bg, float bo,
    f16* __restrict__ dst, int hc0, int wave, int lane)
{
  const int col = lane & 15, krow = lane >> 4;
  f16 hv[4];
#pragma unroll
  for (int j = 0; j < 4; ++j) {
    float iv = acc0[j], gv = acc1[j];
    float fv = __shfl_xor(iv, 8, 64);   // partner lane col^8 holds f at same row
    float ov = __shfl_xor(gv, 8, 64);   // and o
    iv += bi; fv += bf_; gv += bg; ov += bo;
    float cn = sig_(fv) * creg[j] + sig_(iv) * tanhf(gv);  // bounded junk for col>=8
    float hn = sig_(ov) * tanhf(cn);
    creg[j] = cn;
    hv[j] = (f16)hn;
  }
  if (col < 8) {
    f16* pA = dst + (size_t)(16 * wave + krow * 4) * 1024 + hc0 + col;
    f16* pB = pA + 2048;   // rows +2
    unsigned u0 = __builtin_bit_cast(unsigned short, hv[0]);
    unsigned u1 = __builtin_bit_cast(unsigned short, hv[1]);
    unsigned u2 = __builtin_bit_cast(unsigned short, hv[2]);
    unsigned u3 = __builtin_bit_cast(unsigned short, hv[3]);
    asm volatile("global_store_short %0, %1, off sc0 sc1"             :: "v"(pA), "v"(u0) : "memory");
    asm volatile("global_store_short %0, %1, off offset:2048 sc0 sc1" :: "v"(pA), "v"(u1) : "memory");
    asm volatile("global_store_short %0, %1, off sc0 sc1"             :: "v"(pB), "v"(u2) : "memory");
    asm volatile("global_store_short %0, %1, off offset:2048 sc0 sc1" :: "v"(pB), "v"(u3) : "memory");
  }
}

// Layer-0 step: K = x(256, cached fp32->f16 cvt) + s0(1024, sc1-pipelined).
__device__ __forceinline__ void round_L0(
    const float* __restrict__ x, int r,
    const f16* __restrict__ s0in, f16* __restrict__ s0out,
    const f16* __restrict__ wl, float* creg,
    float bi, float bf_, float bg, float bo, int hc0, int wave, int lane)
{
  const int col = lane & 15, krow = lane >> 4;
  f32x4 acc0 = (f32x4){0.f,0.f,0.f,0.f}, acc1 = (f32x4){0.f,0.f,0.f,0.f};
  const f16* Wb = wl + krow * 256 + col * 8;
  const float* xb = x + ((size_t)(16 * wave + col) * TT + r) * INF + krow * 8;
#pragma unroll
  for (int it = 0; it < 8; ++it) {
    float4 u = *(const float4*)(xb + it * 32);
    float4 v = *(const float4*)(xb + it * 32 + 4);
    f16x8 ax;
    ax[0]=(f16)u.x; ax[1]=(f16)u.y; ax[2]=(f16)u.z; ax[3]=(f16)u.w;
    ax[4]=(f16)v.x; ax[5]=(f16)v.y; ax[6]=(f16)v.z; ax[7]=(f16)v.w;
    const f16* wp = Wb + it * 1024;
    f16x8 w0 = *(const f16x8*)(wp);
    f16x8 w1 = *(const f16x8*)(wp + 128);
    acc0 = __builtin_amdgcn_mfma_f32_16x16x32_f16(ax, w0, acc0, 0, 0, 0);
    acc1 = __builtin_amdgcn_mfma_f32_16x16x32_f16(ax, w1, acc1, 0, 0, 0);
  }
  __builtin_amdgcn_sched_barrier(0);
  i32x4 av[32];
  const f16* Ab = s0in + (size_t)(16 * wave + col) * 1024 + krow * 8;
  ISSUE32(Ab, 0);
  VWAIT(24); CONS8(0, 8);
  VWAIT(16); CONS8(8, 16);
  VWAIT(8);  CONS8(16, 24);
  VWAIT(0);  CONS8(24, 32);
  epilogue_store(acc0, acc1, creg, bi, bf_, bg, bo, s0out, hc0, wave, lane);
}

// Layer-1 step: K = s0(1024) + s1(1024), both sc1-pipelined (<=48 loads in flight).
__device__ __forceinline__ void round_L1(
    const f16* __restrict__ s0in, const f16* __restrict__ s1in, f16* __restrict__ s1out,
    const f16* __restrict__ wl, float* creg,
    float bi, float bf_, float bg, float bo, int hc0, int wave, int lane)
{
  const int col = lane & 15, krow = lane >> 4;
  f32x4 acc0 = (f32x4){0.f,0.f,0.f,0.f}, acc1 = (f32x4){0.f,0.f,0.f,0.f};
  const f16* Wb = wl + krow * 256 + col * 8;
  i32x4 av[64];
  const f16* Ab0 = s0in + (size_t)(16 * wave + col) * 1024 + krow * 8;
  const f16* Ab1 = s1in + (size_t)(16 * wave + col) * 1024 + krow * 8;
  ISSUE32(Ab0, 0);
  VWAIT(24); CONS8(0, 0);
  VWAIT(16); CONS8(8, 8);
  ISSUE32(Ab1, 32);
  VWAIT(40); CONS8(16, 16);
  VWAIT(32); CONS8(24, 24);
  VWAIT(24); CONS8(32, 32);
  VWAIT(16); CONS8(40, 40);
  VWAIT(8);  CONS8(48, 48);
  VWAIT(0);  CONS8(56, 56);
  epilogue_store(acc0, acc1, creg, bi, bf_, bg, bo, s1out, hc0, wave, lane);
}

__global__ __launch_bounds__(NTHR, 1) void lstm_fused(
    const float* __restrict__ x,
    const float* __restrict__ w_ih_0, const float* __restrict__ w_hh_0,
    const float* __restrict__ b_ih_0, const float* __restrict__ b_hh_0,
    const float* __restrict__ w_ih_1, const float* __restrict__ w_hh_1,
    const float* __restrict__ b_ih_1, const float* __restrict__ b_hh_1,
    const float* __restrict__ w_fc, const float* __restrict__ b_fc,
    float* __restrict__ out, void* __restrict__ ws)
{
  extern __shared__ char smem[];
  f16* wl = (f16*)smem;
  f16* ws16 = (f16*)ws;
  int* flags = (int*)((char*)ws + FLAGS_OFF_BYTES);

  const int b = blockIdx.x;
  const int tid = threadIdx.x;
  const int wave = tid >> 6, lane = tid & 63;
  const int col = lane & 15;
  const bool isL1 = (b >= NL0B);
  const int bb = isL1 ? b - NL0B : b;
  const int hc0 = bb * 8;
  const int KPHYS = isL1 ? 2048 : 1280;
  bool bail = false;

  // ---- zero the S rings via sc1 stores (h[-1]=c-independent zeros) ----
  {
    const int gt = b * NTHR + tid;          // 0..65535
    if (gt < 32768) {
      i32x4 z = (i32x4){0, 0, 0, 0};
      char* p = (char*)ws + (size_t)gt * 16;
      asm volatile("global_store_dwordx4 %0, %1, off sc0 sc1" :: "v"(p), "v"(z) : "memory");
    }
  }

  // ---- stage fp16 weight slice into LDS, k-chunked [K/8][32][8] ----
  {
    const int c = tid >> 3, kpart = tid & 7;
    const int grp = c >> 3, sub = c & 7;           // gate group i/f/g/o
    const int grow = grp * 1024 + hc0 + sub;       // global gate row
    const int kbound = isL1 ? 1024 : 256;
    const float* srcA = isL1 ? (w_ih_1 + (size_t)grow * 1024) : (w_ih_0 + (size_t)grow * 256);
    const float* srcB = isL1 ? (w_hh_1 + (size_t)grow * 1024) : (w_hh_0 + (size_t)grow * 1024);
    const int kper = KPHYS >> 3;
    for (int k = kpart * kper; k < kpart * kper + kper; k += 4) {
      const float* s = (k < kbound) ? (srcA + k) : (srcB + (k - kbound));
      float4 v = *(const float4*)s;
      f16x4 hv;
      hv[0] = (f16)v.x; hv[1] = (f16)v.y; hv[2] = (f16)v.z; hv[3] = (f16)v.w;
      *(f16x4*)&wl[((size_t)(k >> 3) * 32 + c) * 8 + (k & 7)] = hv;
    }
  }

  // ---- per-lane bias registers ----
  float bi, bf_, bg, bo;
  {
    const float* bI = isL1 ? b_ih_1 : b_ih_0;
    const float* bH = isL1 ? b_hh_1 : b_hh_0;
    const int gi = hc0 + (col & 7);
    bi  = bI[gi]        + bH[gi];
    bf_ = bI[1024 + gi] + bH[1024 + gi];
    bg  = bI[2048 + gi] + bH[2048 + gi];
    bo  = bI[3072 + gi] + bH[3072 + gi];
  }
  float creg[4] = {0.f, 0.f, 0.f, 0.f};

  grid_barrier(flags, 1, bail);

  // ---- 513 pipelined rounds: L0 does step r, L1 does step r-1 ----
  // s0[t] lives in S0[t&1]; s1[t] in S1[t&1].
  for (int r = 0; r <= TT; ++r) {
    if (!isL1) {
      if (r < TT) {
        const f16* s0in = ws16 + (size_t)((r + 1) & 1) * SBUF_ELEMS;   // s0[r-1]
        f16*       s0out = ws16 + (size_t)(r & 1) * SBUF_ELEMS;        // s0[r]
        round_L0(x, r, s0in, s0out, wl, creg, bi, bf_, bg, bo, hc0, wave, lane);
      }
    } else {
      if (r >= 1) {
        const f16* s0in = ws16 + (size_t)((r + 1) & 1) * SBUF_ELEMS;             // s0[r-1]
        const f16* s1in = ws16 + S1_BASE + (size_t)(r & 1) * SBUF_ELEMS;         // s1[r-2]
        f16*       s1out = (f16*)ws16 + S1_BASE + (size_t)((r + 1) & 1) * SBUF_ELEMS; // s1[r-1]
        round_L1(s0in, s1in, s1out, wl, creg, bi, bf_, bg, bo, hc0, wave, lane);
      }
    }
    grid_barrier(flags, r + 2, bail);
  }

  // ---- FC on last timestep: out[:, b] = s1[511] . w_fc[b,:] + b_fc[b] ----
  // s1[511] in S1[1]. Lines were never L1/L2-allocated (all S access was sc1),
  // so plain cached loads fetch fresh data from L3.
  {
    float* red = (float*)smem;   // weights no longer needed
    const f16* A = ws16 + S1_BASE + (size_t)1 * SBUF_ELEMS;
    const int row = tid & 63, kq = tid >> 6;
    const f16* ph = A + (size_t)row * 1024 + kq * 256;
    const float* pw = w_fc + (size_t)b * 1024 + kq * 256;
    float acc = 0.f;
#pragma unroll 4
    for (int k = 0; k < 256; ++k)
      acc = fmaf((float)ph[k], pw[k], acc);
    red[tid] = acc;
    __syncthreads();
    if (tid < 64) {
      float s = red[tid] + red[64 + tid] + red[128 + tid] + red[192 + tid] + b_fc[b];
      out[(size_t)tid * OUTF + b] = s;
    }
  }
}

extern "C" void kernel_launch(void* const* d_in, const int* in_sizes, int n_in,
                              void* d_out, int out_size, void* d_ws, size_t ws_size,
                              hipStream_t stream) {
  const float* x      = (const float*)d_in[0];
  const float* w_ih_0 = (const float*)d_in[1];
  const float* w_hh_0 = (const float*)d_in[2];
  const float* b_ih_0 = (const float*)d_in[3];
  const float* b_hh_0 = (const float*)d_in[4];
  const float* w_ih_1 = (const float*)d_in[5];
  const float* w_hh_1 = (const float*)d_in[6];
  const float* b_ih_1 = (const float*)d_in[7];
  const float* b_hh_1 = (const float*)d_in[8];
  const float* w_fc   = (const float*)d_in[9];
  const float* b_fc   = (const float*)d_in[10];
  float* out = (float*)d_out;
  void* ws = d_ws;

  if (ws_size < WS_BYTES) return;   // clean failure signature, no VM fault

  // Only the flags need host-side zeroing (S rings zeroed in-kernel).
  hipMemsetAsync((char*)d_ws + FLAGS_OFF_BYTES, 0, NBLK * 4, stream);
  hipFuncSetAttribute((const void*)lstm_fused,
                      hipFuncAttributeMaxDynamicSharedMemorySize, LDS_BYTES);

  void* args[] = {
    (void*)&x, (void*)&w_ih_0, (void*)&w_hh_0, (void*)&b_ih_0, (void*)&b_hh_0,
    (void*)&w_ih_1, (void*)&w_hh_1, (void*)&b_ih_1, (void*)&b_hh_1,
    (void*)&w_fc, (void*)&b_fc, (void*)&out, (void*)&ws
  };
  hipError_t err = hipLaunchCooperativeKernel((void*)lstm_fused, dim3(NBLK), dim3(NTHR),
                                              args, LDS_BYTES, stream);
  if (err != hipSuccess) {
    (void)hipGetLastError();
    lstm_fused<<<dim3(NBLK), dim3(NTHR), LDS_BYTES, stream>>>(
        x, w_ih_0, w_hh_0, b_ih_0, b_hh_0, w_ih_1, w_hh_1, b_ih_1, b_hh_1,
        w_fc, b_fc, out, ws);
  }
}